// Round 12
// baseline (597.225 us; speedup 1.0000x reference)
//
#include <hip/hip_runtime.h>
#include <stdint.h>

// ---- problem constants ----
#define DHW         13824      // 24*24*24 spatial positions per (b,c,g) plane
#define NCH         32         // channels C
#define NG          24         // octahedral group order
#define FEATC       72         // NG * N_SEL features per channel
#define KDIM        2304       // NCH * FEATC  (GEMM reduction dim)
#define NHEAD       64
#define TP          16         // spatial positions per block
#define CHS         4          // channels per stage (8 stages/tile)
#define HSN         6          // h-values per thread (4-way h-split)
#define KPE         296        // feat LDS row pitch in bf16 elems (4*72 + 8 pad)
#define KPD         148        // pitch in dwords
#define TILES_PER_B 864        // DHW / TP
#define NTILES      1728       // B * TILES_PER_B
#define NSTAGE      8
#define NB          (NTILES * NSTAGE)   // 13824 blocks
#define KSTEPS      72         // KDIM / 32
#define KSTG        9          // K-steps per stage (4 ch * 72 / 32)
#define OUTN        1769472    // B * NHEAD * DHW  (output floats)
#define WS_WBS      294912     // bytes for swizzled W
#define WS_NEED     (WS_WBS + 2u * OUTN * 4u)   // + two partial-sum planes (proven fit, R11)

typedef __attribute__((ext_vector_type(2))) float    f32x2;
typedef __attribute__((ext_vector_type(8))) short    s16x8;
typedef __attribute__((ext_vector_type(4))) float    f32x4;

// ---- compile-time Cayley table of S4 (matches itertools.permutations order) ----
struct Tables { int cay[NG][NG]; int s1[NG]; int s2[NG]; };

constexpr Tables make_tables() {
    int perms[NG][4] = {};
    int n = 0;
    for (int a = 0; a < 4; ++a)
        for (int b = 0; b < 4; ++b) {
            if (b == a) continue;
            for (int c = 0; c < 4; ++c) {
                if (c == a || c == b) continue;
                int d = 6 - a - b - c;
                perms[n][0] = a; perms[n][1] = b; perms[n][2] = c; perms[n][3] = d;
                ++n;
            }
        }
    int si1 = 0, si2 = 0;
    for (int i = 0; i < NG; ++i) {
        if (perms[i][0] == 1 && perms[i][1] == 0 && perms[i][2] == 2 && perms[i][3] == 3) si1 = i;
        if (perms[i][0] == 1 && perms[i][1] == 2 && perms[i][2] == 3 && perms[i][3] == 0) si2 = i;
    }
    Tables t{};
    for (int p = 0; p < NG; ++p) {
        for (int q = 0; q < NG; ++q) {
            int c0 = perms[p][perms[q][0]];
            int c1 = perms[p][perms[q][1]];
            int c2 = perms[p][perms[q][2]];
            int c3 = perms[p][perms[q][3]];
            int r = 0;
            for (int i = 0; i < NG; ++i)
                if (perms[i][0] == c0 && perms[i][1] == c1 &&
                    perms[i][2] == c2 && perms[i][3] == c3) { r = i; break; }
            t.cay[p][q] = r;
        }
        t.s1[p] = t.cay[p][si1];
        t.s2[p] = t.cay[p][si2];
    }
    return t;
}
constexpr Tables TAB = make_tables();

__device__ __forceinline__ uint32_t f2bf(float f) {   // fp32 -> bf16 (RNE), u16 in low bits
    uint32_t u = __float_as_uint(f);
    u += 0x7fffu + ((u >> 16) & 1u);
    return u >> 16;
}

// ---- kernel 1: W (fp32 64x2304) -> bf16*ln2, pre-swizzled into MFMA A-fragment order.
__global__ __launch_bounds__(256) void prep_w(const float* __restrict__ W,
                                              unsigned short* __restrict__ WbS) {
    int i = blockIdx.x * 256 + threadIdx.x;
    if (i >= NHEAD * KDIM) return;
    int j  = i & 7;
    int t1 = i >> 3;
    int l  = t1 & 63;
    int t2 = t1 >> 6;
    int kk = t2 % KSTEPS;
    int ot = t2 / KSTEPS;
    int o = ot * 16 + (l & 15);
    int k = kk * 32 + ((l >> 4) << 3) + j;
    WbS[i] = (unsigned short)f2bf(W[o * KDIM + k] * 0.69314718055994531f);
}

// ---- kernel 3: y = partial0 + partial1 + bias ----
__global__ __launch_bounds__(256) void reduce_y(const float* __restrict__ part,
                                                const float* __restrict__ bias,
                                                float* __restrict__ y) {
    const int i4 = blockIdx.x * 256 + threadIdx.x;      // float4 index
    const f32x4 v0 = ((const f32x4*)part)[i4];
    const f32x4 v1 = ((const f32x4*)(part + OUTN))[i4];
    const float b  = bias[((i4 * 4) / DHW) & (NHEAD - 1)];
    f32x4 r = v0 + v1;
    r[0] += b; r[1] += b; r[2] += b; r[3] += b;
    ((f32x4*)y)[i4] = r;
}

// tau-core for one h-quarter: HS is compile-time so every xf[] index is static.
template<int HS>
__device__ __forceinline__ void bis_core(const float (&xf)[NG],
                                         float (&tau0)[HSN], f32x2 (&tau12)[HSN]) {
    #pragma unroll
    for (int hh = 0; hh < HSN; ++hh) { tau0[hh] = 0.f; tau12[hh] = (f32x2){0.f, 0.f}; }
    #pragma unroll
    for (int g = 0; g < NG; ++g) {
        const float xg = xf[g];
        const float q0 = xg * xg;
        const f32x2 q12 = {xg * xf[TAB.s1[g]], xg * xf[TAB.s2[g]]};
        #pragma unroll
        for (int hh = 0; hh < HSN; ++hh) {
            const float v = xf[TAB.cay[g][HS * HSN + hh]];   // static register index
            tau0[hh] = fmaf(q0, v, tau0[hh]);
            tau12[hh] = __builtin_elementwise_fma((f32x2){v, v}, q12, tau12[hh]);
        }
    }
}

// ---- kernel 2: fused bispectrum + log-feature + GEMM. 64-VGPR design (R11 lesson:
// >64 VGPR caps at 16 waves/CU; the only path past VALUBusy~45% is the 32-wave tier).
// Each block = one (tile, stage): 16 pos x 4 ch; 256 threads = 16 pos x 4 ch x 4 h-quarters.
// Live state/thread ~52: xf[24] + tau0[6] + tau12[6](f32x2). launch_bounds(256,8) pins
// VGPR<=64 -> 8 blocks/CU. h-quarter is wave-uniform -> template dispatch, no divergence.
// LDS 9.5 KB. Outputs: 8 stage-blocks/tile accumulate into 2 zeroed planes via fp32
// atomicAdd (4 commutative adds/elem; ~1e-6 reorder wobble << 0.113 threshold).
// Tile-major XCD swizzle: a tile's 8 stage-blocks land on one XCD -> x-tile L2 reuse.
__global__ __launch_bounds__(256, 8)
void bispec_fused(
        const float* __restrict__ x,
        const unsigned short* __restrict__ WbS,
        float* __restrict__ part)         // 2 x OUTN partial planes (pre-zeroed)
{
    __shared__ alignas(16) unsigned short featS[TP * KPE];   // 9,472 B

    const int bid = blockIdx.x;
    // XCD-chunked swizzle (NB % 8 == 0), tile-major within chunk:
    const int swz   = (bid & 7) * (NB / 8) + (bid >> 3);
    const int tile  = swz >> 3;          // 0..1727
    const int stage = swz & 7;           // 0..7
    const int bb  = tile / TILES_PER_B;
    const int psp = (tile - bb * TILES_PER_B) * TP;
    const int tid = threadIdx.x;

    const int p0 = tid & 15;             // position
    const int cl = (tid >> 4) & 3;       // local channel 0..3
    const int hs = tid >> 6;             // h-quarter == wave id (uniform per wave)

    // ---------------- phase A: quarter-row per thread ----------------
    {
        const int c0 = stage * CHS + cl;
        // 32-bit divergent index vs uniform base -> saddr-form global_load_dword
        const unsigned idx0 = (unsigned)(bb * NCH + c0) * (NG * DHW) + (unsigned)(psp + p0);
        float xf[NG];
        #pragma unroll
        for (int g = 0; g < NG; ++g) xf[g] = x[idx0 + (unsigned)(g * DHW)];

        float tau0[HSN];
        f32x2 tau12[HSN];
        if      (hs == 0) bis_core<0>(xf, tau0, tau12);
        else if (hs == 1) bis_core<1>(xf, tau0, tau12);
        else if (hs == 2) bis_core<2>(xf, tau0, tau12);
        else              bis_core<3>(xf, tau0, tau12);

        // feature = log2(1 + max(tau,0)); ln2 folded into W. 9 dwords -> LDS (dword stores;
        // offset cl*36 + hs*9 is only 4B-aligned for odd hs).
        uint32_t* dst = (uint32_t*)featS + p0 * KPD + cl * 36 + hs * 9;
        #pragma unroll
        for (int hh = 0; hh < HSN; hh += 2) {
            float f0 = __log2f(1.f + fmaxf(tau0[hh],       0.f));
            float f1 = __log2f(1.f + fmaxf(tau12[hh][0],   0.f));
            float f2 = __log2f(1.f + fmaxf(tau12[hh][1],   0.f));
            float f3 = __log2f(1.f + fmaxf(tau0[hh+1],     0.f));
            float f4 = __log2f(1.f + fmaxf(tau12[hh+1][0], 0.f));
            float f5 = __log2f(1.f + fmaxf(tau12[hh+1][1], 0.f));
            const int bw = (hh >> 1) * 3;
            dst[bw + 0] = f2bf(f0) | (f2bf(f1) << 16);
            dst[bw + 1] = f2bf(f2) | (f2bf(f3) << 16);
            dst[bw + 2] = f2bf(f4) | (f2bf(f5) << 16);
        }
    }
    __syncthreads();

    // -------- phase B: accumulate this stage's 9 K-steps, atomic into plane --------
    {
        const int wv = hs;               // wave -> o-tile (16 heads)
        const int l  = tid & 63;
        const int ln = l & 15;           // position col
        const int lh = l >> 4;           // k sub-block

        f32x4 acc = {0.f, 0.f, 0.f, 0.f};
        const s16x8* wbase = (const s16x8*)WbS
                           + ((size_t)(wv * KSTEPS + stage * KSTG) * 64 + l);
        const unsigned short* fb = &featS[ln * KPE + lh * 8];

        #pragma unroll
        for (int kk = 0; kk < KSTG; ++kk) {
            s16x8 a = wbase[(size_t)kk * 64];
            s16x8 b = *(const s16x8*)(fb + kk * 32);
            acc = __builtin_amdgcn_mfma_f32_16x16x32_bf16(a, b, acc, 0, 0, 0);
        }

        float* plane = part + (size_t)(stage & 1) * OUTN;
        const size_t ybase = (size_t)bb * NHEAD * DHW + (size_t)(psp + ln);
        #pragma unroll
        for (int j = 0; j < 4; ++j) {
            const int o = wv * 16 + lh * 4 + j;
            atomicAdd(&plane[ybase + (size_t)o * DHW], acc[j]);
        }
    }
}

extern "C" void kernel_launch(void* const* d_in, const int* in_sizes, int n_in,
                              void* d_out, int out_size, void* d_ws, size_t ws_size,
                              hipStream_t stream) {
    const float* x    = (const float*)d_in[0];
    const float* W    = (const float*)d_in[1];
    const float* bias = (const float*)d_in[2];
    unsigned short* WbS = (unsigned short*)d_ws;            // 294,912 B
    float* part = (float*)((char*)d_ws + WS_WBS);           // 2 x OUTN floats (R11: fits)

    prep_w<<<dim3((NHEAD * KDIM + 255) / 256), dim3(256), 0, stream>>>(W, WbS);
    hipMemsetAsync(part, 0, 2u * OUTN * sizeof(float), stream);
    bispec_fused<<<dim3(NB), dim3(256), 0, stream>>>(x, WbS, part);
    reduce_y<<<dim3(OUTN / 4 / 256), dim3(256), 0, stream>>>(part, bias, (float*)d_out);
}

// Round 13
// 70.587 us; speedup vs baseline: 8.4609x; 8.4609x over previous
//
#include <hip/hip_runtime.h>
#include <stdint.h>

// ---- problem constants ----
#define DHW         13824      // 24*24*24 spatial positions per (b,c,g) plane
#define NCH         32         // channels C
#define NG          24         // octahedral group order
#define FEATC       72         // NG * N_SEL features per channel
#define KDIM        2304       // NCH * FEATC  (GEMM reduction dim)
#define NHEAD       64
#define TP          16         // spatial positions per block
#define CHS         16         // channels per stage (2 stages)
#define KPE         1160       // feat LDS row pitch in bf16 elems (16*72 + 8 pad)
#define TILES_PER_B 864        // DHW / TP
#define NTILES      1728       // B * TILES_PER_B
#define KSTEPS      72         // KDIM / 32
#define KSTG        36         // K-steps per stage
#define KQ          9          // K-steps per wave per stage (k-split across 4 waves)
#define OUTN        1769472    // B * NHEAD * DHW  (output floats)
#define WS_WBS      294912     // bytes for swizzled W
#define WS_NEED     (WS_WBS + 2u * OUTN * 4u)   // + two partial-sum planes (proven fit, R11)

typedef __attribute__((ext_vector_type(2))) float    f32x2;
typedef __attribute__((ext_vector_type(8))) short    s16x8;
typedef __attribute__((ext_vector_type(4))) float    f32x4;
typedef __attribute__((ext_vector_type(4))) uint32_t u32x4;

// ---- compile-time Cayley table of S4 (matches itertools.permutations order) ----
struct Tables { int cay[NG][NG]; int s1[NG]; int s2[NG]; };

constexpr Tables make_tables() {
    int perms[NG][4] = {};
    int n = 0;
    for (int a = 0; a < 4; ++a)
        for (int b = 0; b < 4; ++b) {
            if (b == a) continue;
            for (int c = 0; c < 4; ++c) {
                if (c == a || c == b) continue;
                int d = 6 - a - b - c;
                perms[n][0] = a; perms[n][1] = b; perms[n][2] = c; perms[n][3] = d;
                ++n;
            }
        }
    int si1 = 0, si2 = 0;
    for (int i = 0; i < NG; ++i) {
        if (perms[i][0] == 1 && perms[i][1] == 0 && perms[i][2] == 2 && perms[i][3] == 3) si1 = i;
        if (perms[i][0] == 1 && perms[i][1] == 2 && perms[i][2] == 3 && perms[i][3] == 0) si2 = i;
    }
    Tables t{};
    for (int p = 0; p < NG; ++p) {
        for (int q = 0; q < NG; ++q) {
            int c0 = perms[p][perms[q][0]];
            int c1 = perms[p][perms[q][1]];
            int c2 = perms[p][perms[q][2]];
            int c3 = perms[p][perms[q][3]];
            int r = 0;
            for (int i = 0; i < NG; ++i)
                if (perms[i][0] == c0 && perms[i][1] == c1 &&
                    perms[i][2] == c2 && perms[i][3] == c3) { r = i; break; }
            t.cay[p][q] = r;
        }
        t.s1[p] = t.cay[p][si1];
        t.s2[p] = t.cay[p][si2];
    }
    return t;
}
constexpr Tables TAB = make_tables();

__device__ __forceinline__ uint32_t f2bf(float f) {   // fp32 -> bf16 (RNE), u16 in low bits
    uint32_t u = __float_as_uint(f);
    u += 0x7fffu + ((u >> 16) & 1u);
    return u >> 16;
}

// ---- kernel 1: W (fp32 64x2304) -> bf16*ln2, pre-swizzled into MFMA A-fragment order.
__global__ __launch_bounds__(256) void prep_w(const float* __restrict__ W,
                                              unsigned short* __restrict__ WbS) {
    int i = blockIdx.x * 256 + threadIdx.x;
    if (i >= NHEAD * KDIM) return;
    int j  = i & 7;
    int t1 = i >> 3;
    int l  = t1 & 63;
    int t2 = t1 >> 6;
    int kk = t2 % KSTEPS;
    int ot = t2 / KSTEPS;
    int o = ot * 16 + (l & 15);
    int k = kk * 32 + ((l >> 4) << 3) + j;
    WbS[i] = (unsigned short)f2bf(W[o * KDIM + k] * 0.69314718055994531f);
}

// ---- kernel 3: y = partial0 + partial1 + bias (split path only) ----
__global__ __launch_bounds__(256) void reduce_y(const float* __restrict__ part,
                                                const float* __restrict__ bias,
                                                float* __restrict__ y) {
    const int i4 = blockIdx.x * 256 + threadIdx.x;      // float4 index
    const f32x4 v0 = ((const f32x4*)part)[i4];
    const f32x4 v1 = ((const f32x4*)(part + OUTN))[i4];
    const float b  = bias[((i4 * 4) / DHW) & (NHEAD - 1)];
    f32x4 r = v0 + v1;
    r[0] += b; r[1] += b; r[2] += b; r[3] += b;
    ((f32x4*)y)[i4] = r;
}

// ---- kernel 2: fused bispectrum + log-feature + 64-head GEMM, 16 positions/block.
// 256 threads (4 waves), launch_bounds(256,2) -- the ONLY allocator surface that gives
// honest VGPRs (R12: min-waves=8 request -> 32-VGPR panic + 1.6GB spills; R2-R6: 512
// threads -> 64-VGPR pin + spills. R7/R9/R11: this surface -> 72-92 VGPR, zero spill).
// Phase A: one full (c,p) row per thread (unchanged from R11).
// Phase B (R13 rewrite): K split ACROSS waves -- wave w does k-steps [9w,9w+9) for ALL
// four o-tiles: 1 shared ds_read + 4 independent a-loads + 4 independent MFMA chains
// per step (ds_reads/block 144->36, chain depth 18->9, + 1-step b prefetch). Epilogue:
// cross-wave k-reduction through LDS (overlays dead featS), wave w stores o-tile w.
template<int SPLIT>
__global__ __launch_bounds__(256, 2)
void bispec_fused(
        const float* __restrict__ x,
        const unsigned short* __restrict__ WbS,
        const float* __restrict__ bias,
        float* __restrict__ out)          // SPLIT ? partial planes : final y
{
    __shared__ alignas(16) unsigned short featS[TP * KPE];   // 37,120 B -> 4 blocks/CU

    const int bid = blockIdx.x;
    const int NB  = SPLIT ? NTILES * 2 : NTILES;
    // XCD-chunked swizzle (NB % 8 == 0); bijection bid -> (tile, stage)
    const int swz   = (bid & 7) * (NB / 8) + (bid >> 3);
    const int tile  = SPLIT ? (swz % NTILES) : swz;
    const int sbeg  = SPLIT ? (swz / NTILES) : 0;
    const int send  = SPLIT ? sbeg + 1 : 2;
    const int bb  = tile / TILES_PER_B;
    const int psp = (tile - bb * TILES_PER_B) * TP;
    const int tid = threadIdx.x;

    const int p0 = tid & 15;          // position within tile (phase A)
    const int cl = tid >> 4;          // local channel 0..15 (phase A)
    const int w  = tid >> 6;          // wave: k-quarter in phase B, o-tile in epilogue
    const int l  = tid & 63;
    const int ln = l & 15;            // position col (phase B)
    const int lh = l >> 4;            // k sub-block (phase B)

    f32x4 accA = {0.f, 0.f, 0.f, 0.f};   // o-tile 0 (heads  0..15)
    f32x4 accB = {0.f, 0.f, 0.f, 0.f};   // o-tile 1 (heads 16..31)
    f32x4 accC = {0.f, 0.f, 0.f, 0.f};   // o-tile 2 (heads 32..47)
    f32x4 accD = {0.f, 0.f, 0.f, 0.f};   // o-tile 3 (heads 48..63)

    #pragma unroll 1                  // stages strictly sequential: no live-range merge
    for (int stage = sbeg; stage < send; ++stage) {
        // ---------------- phase A: one full (c,p) row per thread ----------------
        {
            const int c0 = stage * CHS + cl;
            // 32-bit divergent index vs uniform base -> saddr-form global_load_dword
            const unsigned idx0 = (unsigned)(bb * NCH + c0) * (NG * DHW) + (unsigned)(psp + p0);
            float xf[NG];
            #pragma unroll
            for (int g = 0; g < NG; ++g) xf[g] = x[idx0 + (unsigned)(g * DHW)];

            float tau0[NG];          // s = identity component
            f32x2 tau12[NG];         // (s1, s2) components -> v_pk_fma_f32
            #pragma unroll
            for (int h = 0; h < NG; ++h) { tau0[h] = 0.f; tau12[h] = (f32x2){0.f, 0.f}; }
            #pragma unroll
            for (int g = 0; g < NG; ++g) {
                const float xg = xf[g];
                const float q0 = xg * xg;
                const f32x2 q12 = {xg * xf[TAB.s1[g]], xg * xf[TAB.s2[g]]};
                #pragma unroll
                for (int h = 0; h < NG; ++h) {
                    const float v = xf[TAB.cay[g][h]];   // static register index
                    tau0[h] = fmaf(q0, v, tau0[h]);
                    tau12[h] = __builtin_elementwise_fma((f32x2){v, v}, q12, tau12[h]);
                }
            }
            // feature = log2(1 + max(tau,0))  [ln2 folded into W; log2(1)=0 exact]
            uint32_t pk[FEATC / 2];
            #pragma unroll
            for (int h = 0; h < NG; h += 2) {
                float f0 = __log2f(1.f + fmaxf(tau0[h],       0.f));
                float f1 = __log2f(1.f + fmaxf(tau12[h][0],   0.f));
                float f2 = __log2f(1.f + fmaxf(tau12[h][1],   0.f));
                float f3 = __log2f(1.f + fmaxf(tau0[h+1],     0.f));
                float f4 = __log2f(1.f + fmaxf(tau12[h+1][0], 0.f));
                float f5 = __log2f(1.f + fmaxf(tau12[h+1][1], 0.f));
                const int bw = (h >> 1) * 3;
                pk[bw + 0] = f2bf(f0) | (f2bf(f1) << 16);
                pk[bw + 1] = f2bf(f2) | (f2bf(f3) << 16);
                pk[bw + 2] = f2bf(f4) | (f2bf(f5) << 16);
            }
            uint32_t* dst = (uint32_t*)&featS[p0 * KPE + cl * FEATC];   // 16B-aligned
            #pragma unroll
            for (int i = 0; i < FEATC / 2; i += 4) {
                u32x4 v; v[0] = pk[i]; v[1] = pk[i+1]; v[2] = pk[i+2]; v[3] = pk[i+3];
                *(u32x4*)(dst + i) = v;
            }
        }
        __syncthreads();

        // ---- phase B: wave w accumulates k-steps [9w, 9w+9) for ALL 4 o-tiles ----
        {
            const unsigned kbase = (unsigned)(stage * KSTG + w * KQ);
            const unsigned short* fb = &featS[ln * KPE + (w * KQ) * 32 + lh * 8];
            const s16x8* wb = (const s16x8*)WbS;

            s16x8 bc = *(const s16x8*)(fb);          // b prefetch (shared by 4 o-tiles)
            #pragma unroll
            for (int kk = 0; kk < KQ; ++kk) {
                s16x8 bn = bc;
                if (kk + 1 < KQ) bn = *(const s16x8*)(fb + (kk + 1) * 32);
                const unsigned ai = (kbase + (unsigned)kk) * 64u + (unsigned)l;
                s16x8 a0 = wb[ai];
                s16x8 a1 = wb[ai + 1u * KSTEPS * 64u];
                s16x8 a2 = wb[ai + 2u * KSTEPS * 64u];
                s16x8 a3 = wb[ai + 3u * KSTEPS * 64u];
                accA = __builtin_amdgcn_mfma_f32_16x16x32_bf16(a0, bc, accA, 0, 0, 0);
                accB = __builtin_amdgcn_mfma_f32_16x16x32_bf16(a1, bc, accB, 0, 0, 0);
                accC = __builtin_amdgcn_mfma_f32_16x16x32_bf16(a2, bc, accC, 0, 0, 0);
                accD = __builtin_amdgcn_mfma_f32_16x16x32_bf16(a3, bc, accD, 0, 0, 0);
                bc = bn;
            }
        }
        __syncthreads();   // all ds_reads done before LDS reuse (next stage A / redS)
    }

    // ---- epilogue: cross-wave k-reduction (featS dead -> overlay), store o-tile w ----
    f32x4* redS = (f32x4*)featS;      // 4 waves x 4 o-tiles x 64 lanes x 16B = 16 KB
    redS[(w * 4 + 0) * 64 + l] = accA;
    redS[(w * 4 + 1) * 64 + l] = accB;
    redS[(w * 4 + 2) * 64 + l] = accC;
    redS[(w * 4 + 3) * 64 + l] = accD;
    __syncthreads();
    f32x4 r = redS[(0 * 4 + w) * 64 + l] + redS[(1 * 4 + w) * 64 + l]
            + redS[(2 * 4 + w) * 64 + l] + redS[(3 * 4 + w) * 64 + l];

    // D layout: col = lane&15 (position), row = (lane>>4)*4 + j (head within o-tile w)
    const size_t obase = (SPLIT ? (size_t)sbeg * OUTN : 0)
                       + (size_t)bb * NHEAD * DHW + (size_t)(psp + ln);
    #pragma unroll
    for (int j = 0; j < 4; ++j) {
        const int o = w * 16 + lh * 4 + j;
        const float bv = SPLIT ? 0.f : bias[o];
        out[obase + (size_t)o * DHW] = r[j] + bv;
    }
}

extern "C" void kernel_launch(void* const* d_in, const int* in_sizes, int n_in,
                              void* d_out, int out_size, void* d_ws, size_t ws_size,
                              hipStream_t stream) {
    const float* x    = (const float*)d_in[0];
    const float* W    = (const float*)d_in[1];
    const float* bias = (const float*)d_in[2];
    unsigned short* WbS = (unsigned short*)d_ws;            // 294,912 B
    float* part = (float*)((char*)d_ws + WS_WBS);           // 2 x OUTN floats (R11: fits)

    prep_w<<<dim3((NHEAD * KDIM + 255) / 256), dim3(256), 0, stream>>>(W, WbS);
    if (ws_size >= (size_t)WS_NEED) {
        bispec_fused<1><<<dim3(NTILES * 2), dim3(256), 0, stream>>>(x, WbS, bias, part);
        reduce_y<<<dim3(OUTN / 4 / 256), dim3(256), 0, stream>>>(part, bias, (float*)d_out);
    } else {
        bispec_fused<0><<<dim3(NTILES), dim3(256), 0, stream>>>(x, WbS, bias, (float*)d_out);
    }
}

// Round 14
// 61.931 us; speedup vs baseline: 9.6433x; 1.1398x over previous
//
#include <hip/hip_runtime.h>
#include <stdint.h>

// ---- problem constants ----
#define DHW         13824      // 24*24*24 spatial positions per (b,c,g) plane
#define NCH         32         // channels C
#define NG          24         // octahedral group order
#define KDIM        2304       // ORIGINAL GEMM K (32 ch * 72)
#define NHEAD       64
#define TP          16         // spatial positions per block
#define CHS         16         // channels per stage (2 stages)
#define NFC         60         // distinct features/channel after t1-fold (24+12+24)
#define FPC         64         // padded features/channel (4 zero pad) -> clean k-steps
#define KP2         2048       // padded folded K: 2 stages x 16 ch x 64
#define KS2         64         // padded K-steps total (KP2/32)
#define KPSTG       32         // K-steps per stage
#define KQ          8          // K-steps per wave per stage (32/4, exact)
#define KPE         1032       // LDS row pitch in bf16 elems (16*64 + 8 pad -> 4-bank skew)
#define TILES_PER_B 864        // DHW / TP
#define NTILES      1728       // B * TILES_PER_B
#define OUTN        1769472    // B * NHEAD * DHW  (output floats)
#define WS_WBS      294912     // ws bytes reserved for swizzled W (uses 262,144)
#define WS_NEED     (WS_WBS + 2u * OUTN * 4u)   // + two partial-sum planes (proven fit, R11)

typedef __attribute__((ext_vector_type(2))) float    f32x2;
typedef __attribute__((ext_vector_type(8))) short    s16x8;
typedef __attribute__((ext_vector_type(4))) float    f32x4;
typedef __attribute__((ext_vector_type(4))) uint32_t u32x4;

// ---- compile-time Cayley table of S4 (matches itertools.permutations order) ----
// Extras for the t1-fold: t1h[h] = t1*h (left mult), rep[12] = orbit representatives
// of the pairing tau[h][1] == tau[t1*h][1]  (t1 = sel[1] = (1,0,2,3), an involution).
struct Tables { int cay[NG][NG]; int s1[NG]; int s2[NG]; int t1h[NG]; int rep[12]; };

constexpr Tables make_tables() {
    int perms[NG][4] = {};
    int n = 0;
    for (int a = 0; a < 4; ++a)
        for (int b = 0; b < 4; ++b) {
            if (b == a) continue;
            for (int c = 0; c < 4; ++c) {
                if (c == a || c == b) continue;
                int d = 6 - a - b - c;
                perms[n][0] = a; perms[n][1] = b; perms[n][2] = c; perms[n][3] = d;
                ++n;
            }
        }
    int si1 = 0, si2 = 0;
    for (int i = 0; i < NG; ++i) {
        if (perms[i][0] == 1 && perms[i][1] == 0 && perms[i][2] == 2 && perms[i][3] == 3) si1 = i;
        if (perms[i][0] == 1 && perms[i][1] == 2 && perms[i][2] == 3 && perms[i][3] == 0) si2 = i;
    }
    Tables t{};
    for (int p = 0; p < NG; ++p) {
        for (int q = 0; q < NG; ++q) {
            int c0 = perms[p][perms[q][0]];
            int c1 = perms[p][perms[q][1]];
            int c2 = perms[p][perms[q][2]];
            int c3 = perms[p][perms[q][3]];
            int r = 0;
            for (int i = 0; i < NG; ++i)
                if (perms[i][0] == c0 && perms[i][1] == c1 &&
                    perms[i][2] == c2 && perms[i][3] == c3) { r = i; break; }
            t.cay[p][q] = r;
        }
        t.s1[p] = t.cay[p][si1];
        t.s2[p] = t.cay[p][si2];
    }
    for (int h = 0; h < NG; ++h) t.t1h[h] = t.cay[si1][h];   // t1 o h
    int nr = 0;
    for (int h = 0; h < NG; ++h) if (h < t.t1h[h]) t.rep[nr++] = h;   // 12 pairs, no fixpoints
    return t;
}
constexpr Tables TAB = make_tables();

__device__ __forceinline__ uint32_t f2bf(float f) {   // fp32 -> bf16 (RNE), u16 in low bits
    uint32_t u = __float_as_uint(f);
    u += 0x7fffu + ((u >> 16) & 1u);
    return u >> 16;
}

// ---- kernel 1: fold + swizzle W. Folded feature order per channel:
// f in [0,24): tau0[h=f] | [24,36): tau1[rep[f-24]] (W summed over the pair) |
// [36,60): tau2[h=f-36] | [60,64): zero pad. ln2 folded in (phase A uses log2).
// WbS[((ot*KS2 + kk)*64 + lane)*8 + j] = W'[ot*16 + (lane&15)][kk*32 + (lane>>4)*8 + j]
__global__ __launch_bounds__(256) void prep_w(const float* __restrict__ W,
                                              unsigned short* __restrict__ WbS) {
    int i = blockIdx.x * 256 + threadIdx.x;      // < 64*2048 = 131072
    int j  = i & 7;
    int t1_ = i >> 3;
    int l  = t1_ & 63;
    int t2_ = t1_ >> 6;
    int kk = t2_ & (KS2 - 1);
    int ot = t2_ >> 6;
    int o = ot * 16 + (l & 15);
    int k = kk * 32 + ((l >> 4) << 3) + j;       // 0..2047 folded-K column
    int stage = k >> 10;                         // 0..1
    int q     = k & 1023;
    int c = stage * CHS + (q >> 6);              // channel
    int f = q & 63;                              // folded feature index
    const float* Wo = W + o * KDIM + c * 72;
    float val = 0.f;
    if (f < 24)      val = Wo[f * 3 + 0];
    else if (f < 36) { int h = TAB.rep[f - 24]; val = Wo[h * 3 + 1] + Wo[TAB.t1h[h] * 3 + 1]; }
    else if (f < 60) { int h = f - 36;          val = Wo[h * 3 + 2]; }
    WbS[i] = (unsigned short)f2bf(val * 0.69314718055994531f);
}

// ---- kernel 3: y = partial0 + partial1 + bias (split path only) ----
__global__ __launch_bounds__(256) void reduce_y(const float* __restrict__ part,
                                                const float* __restrict__ bias,
                                                float* __restrict__ y) {
    const int i4 = blockIdx.x * 256 + threadIdx.x;      // float4 index
    const f32x4 v0 = ((const f32x4*)part)[i4];
    const f32x4 v1 = ((const f32x4*)(part + OUTN))[i4];
    const float b  = bias[((i4 * 4) / DHW) & (NHEAD - 1)];
    f32x4 r = v0 + v1;
    r[0] += b; r[1] += b; r[2] += b; r[3] += b;
    ((f32x4*)y)[i4] = r;
}

// ---- kernel 2: fused bispectrum + log-feature + 64-head GEMM, 16 positions/block.
// 256 threads (4 waves), launch_bounds(256,2) -- the only healthy allocator surface
// (R7/R9/R11/R13: 68-92 VGPR, zero spill; everything else spilled or panicked).
// R14: t1-fold symmetry tau[h][1]==tau[t1h][1] -> compute 12 tau1 instead of 24;
// pack (tau0,tau2) in v_pk_fma_f32; K 2304->1920 (+pad->2048): tau-core -21% inst,
// tail -17%, phase-B MFMA/ds_read -11%, LDS 37->33 KB.
// Phase B: K split across waves (R13): wave w does k-steps [8w,8w+8) of the stage for
// all 4 o-tiles (1 shared ds_read + 4 a-loads + 4 indep MFMA per step), cross-wave
// k-reduction through LDS at the end, wave w stores o-tile w.
template<int SPLIT>
__global__ __launch_bounds__(256, 2)
void bispec_fused(
        const float* __restrict__ x,
        const unsigned short* __restrict__ WbS,
        const float* __restrict__ bias,
        float* __restrict__ out)          // SPLIT ? partial planes : final y
{
    __shared__ alignas(16) unsigned short featS[TP * KPE];   // 33,024 B

    const int bid = blockIdx.x;
    const int NB  = SPLIT ? NTILES * 2 : NTILES;
    // XCD-chunked swizzle (NB % 8 == 0); bijection bid -> (tile, stage)
    const int swz   = (bid & 7) * (NB / 8) + (bid >> 3);
    const int tile  = SPLIT ? (swz % NTILES) : swz;
    const int sbeg  = SPLIT ? (swz / NTILES) : 0;
    const int send  = SPLIT ? sbeg + 1 : 2;
    const int bb  = tile / TILES_PER_B;
    const int psp = (tile - bb * TILES_PER_B) * TP;
    const int tid = threadIdx.x;

    const int p0 = tid & 15;          // position within tile (phase A)
    const int cl = tid >> 4;          // local channel 0..15 (phase A)
    const int w  = tid >> 6;          // wave: k-quarter in phase B, o-tile in epilogue
    const int l  = tid & 63;
    const int ln = l & 15;            // position col (phase B)
    const int lh = l >> 4;            // k sub-block (phase B)

    f32x4 accA = {0.f, 0.f, 0.f, 0.f};   // o-tile 0 (heads  0..15)
    f32x4 accB = {0.f, 0.f, 0.f, 0.f};   // o-tile 1 (heads 16..31)
    f32x4 accC = {0.f, 0.f, 0.f, 0.f};   // o-tile 2 (heads 32..47)
    f32x4 accD = {0.f, 0.f, 0.f, 0.f};   // o-tile 3 (heads 48..63)

    #pragma unroll 1                  // stages strictly sequential: no live-range merge
    for (int stage = sbeg; stage < send; ++stage) {
        // ---------------- phase A: one full (c,p) row per thread ----------------
        {
            const int c0 = stage * CHS + cl;
            // 32-bit divergent index vs uniform base -> saddr-form global_load_dword
            const unsigned idx0 = (unsigned)(bb * NCH + c0) * (NG * DHW) + (unsigned)(psp + p0);
            float xf[NG];
            #pragma unroll
            for (int g = 0; g < NG; ++g) xf[g] = x[idx0 + (unsigned)(g * DHW)];

            f32x2 tau02[NG];         // (tau0, tau2) packed -> v_pk_fma_f32
            float tau1[12];          // only the 12 distinct s1 values (t1-fold)
            #pragma unroll
            for (int h = 0; h < NG; ++h) tau02[h] = (f32x2){0.f, 0.f};
            #pragma unroll
            for (int r = 0; r < 12; ++r) tau1[r] = 0.f;
            #pragma unroll
            for (int g = 0; g < NG; ++g) {
                const float xg = xf[g];
                const f32x2 q02 = (f32x2){xg, xg} * (f32x2){xg, xf[TAB.s2[g]]};
                const float q1 = xg * xf[TAB.s1[g]];
                #pragma unroll
                for (int h = 0; h < NG; ++h) {
                    const float v = xf[TAB.cay[g][h]];   // static register index
                    tau02[h] = __builtin_elementwise_fma((f32x2){v, v}, q02, tau02[h]);
                }
                #pragma unroll
                for (int r = 0; r < 12; ++r) {
                    const float v = xf[TAB.cay[g][TAB.rep[r]]];   // static register index
                    tau1[r] = fmaf(q1, v, tau1[r]);
                }
            }
            // feature = log2(1 + max(tau,0))  [ln2 folded into W; log2(1)=0 exact]
            uint32_t pk[FPC / 2];
            #pragma unroll
            for (int i = 0; i < 12; ++i) {        // f 0..23: tau0
                float a = __log2f(1.f + fmaxf(tau02[2*i][0],   0.f));
                float b = __log2f(1.f + fmaxf(tau02[2*i+1][0], 0.f));
                pk[i] = f2bf(a) | (f2bf(b) << 16);
            }
            #pragma unroll
            for (int i = 0; i < 6; ++i) {         // f 24..35: tau1 reps
                float a = __log2f(1.f + fmaxf(tau1[2*i],   0.f));
                float b = __log2f(1.f + fmaxf(tau1[2*i+1], 0.f));
                pk[12 + i] = f2bf(a) | (f2bf(b) << 16);
            }
            #pragma unroll
            for (int i = 0; i < 12; ++i) {        // f 36..59: tau2
                float a = __log2f(1.f + fmaxf(tau02[2*i][1],   0.f));
                float b = __log2f(1.f + fmaxf(tau02[2*i+1][1], 0.f));
                pk[18 + i] = f2bf(a) | (f2bf(b) << 16);
            }
            pk[30] = 0u; pk[31] = 0u;             // f 60..63: pad (W' columns are zero)
            // row: p0*2064B (16B-aligned) + cl*128B (16B-aligned) -> 8 x b128 stores
            uint32_t* dst = (uint32_t*)&featS[p0 * KPE + cl * FPC];
            #pragma unroll
            for (int i = 0; i < FPC / 2; i += 4) {
                u32x4 v; v[0] = pk[i]; v[1] = pk[i+1]; v[2] = pk[i+2]; v[3] = pk[i+3];
                *(u32x4*)(dst + i) = v;
            }
        }
        __syncthreads();

        // ---- phase B: wave w accumulates k-steps [8w, 8w+8) for ALL 4 o-tiles ----
        {
            const unsigned kb = (unsigned)(stage * KPSTG + w * KQ);   // global k-step
            const unsigned short* fb = &featS[ln * KPE + (w * KQ) * 32 + lh * 8];
            const s16x8* wb = (const s16x8*)WbS;

            s16x8 bc = *(const s16x8*)(fb);          // b prefetch (shared by 4 o-tiles)
            #pragma unroll
            for (int kk = 0; kk < KQ; ++kk) {
                s16x8 bn = bc;
                if (kk + 1 < KQ) bn = *(const s16x8*)(fb + (kk + 1) * 32);
                const unsigned ai = (kb + (unsigned)kk) * 64u + (unsigned)l;
                s16x8 a0 = wb[ai];
                s16x8 a1 = wb[ai + 1u * KS2 * 64u];
                s16x8 a2 = wb[ai + 2u * KS2 * 64u];
                s16x8 a3 = wb[ai + 3u * KS2 * 64u];
                accA = __builtin_amdgcn_mfma_f32_16x16x32_bf16(a0, bc, accA, 0, 0, 0);
                accB = __builtin_amdgcn_mfma_f32_16x16x32_bf16(a1, bc, accB, 0, 0, 0);
                accC = __builtin_amdgcn_mfma_f32_16x16x32_bf16(a2, bc, accC, 0, 0, 0);
                accD = __builtin_amdgcn_mfma_f32_16x16x32_bf16(a3, bc, accD, 0, 0, 0);
                bc = bn;
            }
        }
        __syncthreads();   // all ds_reads done before LDS reuse (next stage A / redS)
    }

    // ---- epilogue: cross-wave k-reduction (featS dead -> overlay), store o-tile w ----
    f32x4* redS = (f32x4*)featS;      // 4 waves x 4 o-tiles x 64 lanes x 16B = 16 KB
    redS[(w * 4 + 0) * 64 + l] = accA;
    redS[(w * 4 + 1) * 64 + l] = accB;
    redS[(w * 4 + 2) * 64 + l] = accC;
    redS[(w * 4 + 3) * 64 + l] = accD;
    __syncthreads();
    f32x4 r = redS[(0 * 4 + w) * 64 + l] + redS[(1 * 4 + w) * 64 + l]
            + redS[(2 * 4 + w) * 64 + l] + redS[(3 * 4 + w) * 64 + l];

    // D layout: col = lane&15 (position), row = (lane>>4)*4 + j (head within o-tile w)
    const size_t obase = (SPLIT ? (size_t)sbeg * OUTN : 0)
                       + (size_t)bb * NHEAD * DHW + (size_t)(psp + ln);
    #pragma unroll
    for (int j = 0; j < 4; ++j) {
        const int o = w * 16 + lh * 4 + j;
        const float bv = SPLIT ? 0.f : bias[o];
        out[obase + (size_t)o * DHW] = r[j] + bv;
    }
}

extern "C" void kernel_launch(void* const* d_in, const int* in_sizes, int n_in,
                              void* d_out, int out_size, void* d_ws, size_t ws_size,
                              hipStream_t stream) {
    const float* x    = (const float*)d_in[0];
    const float* W    = (const float*)d_in[1];
    const float* bias = (const float*)d_in[2];
    unsigned short* WbS = (unsigned short*)d_ws;            // 262,144 B used
    float* part = (float*)((char*)d_ws + WS_WBS);           // 2 x OUTN floats (R11: fits)

    prep_w<<<dim3(NHEAD * KP2 / 256), dim3(256), 0, stream>>>(W, WbS);
    if (ws_size >= (size_t)WS_NEED) {
        bispec_fused<1><<<dim3(NTILES * 2), dim3(256), 0, stream>>>(x, WbS, bias, part);
        reduce_y<<<dim3(OUTN / 4 / 256), dim3(256), 0, stream>>>(part, bias, (float*)d_out);
    } else {
        bispec_fused<0><<<dim3(NTILES), dim3(256), 0, stream>>>(x, WbS, bias, (float*)d_out);
    }
}